// Round 1
// baseline (2533.462 us; speedup 1.0000x reference)
//
#include <hip/hip_runtime.h>

typedef __bf16 bf16x8 __attribute__((ext_vector_type(8)));
typedef float f32x4 __attribute__((ext_vector_type(4)));
typedef unsigned short u16x8 __attribute__((ext_vector_type(8)));
typedef unsigned short u16x4 __attribute__((ext_vector_type(4)));
typedef unsigned short u16;

#define N_NODES 50000
#define N_EDGES 800000
#define DD 128

__device__ __forceinline__ u16 f2bf(float f){
  unsigned int u = __float_as_uint(f);
  unsigned int r = (u + 0x7FFFu + ((u >> 16) & 1u)) >> 16;
  return (u16)r;
}
__device__ __forceinline__ float bf2f(u16 s){
  return __uint_as_float(((unsigned int)s) << 16);
}
// XOR swizzle: element index within a [128][128] u16 LDS tile.
// XORs bits 3..5 of k with row&7 -> 8-elem blocks stay contiguous, 16B aligned.
__device__ __forceinline__ int SW(int row, int k){ return row*128 + (k ^ ((row & 7) << 3)); }

// ---------------- K0: convert W matrices to bf16, transposed (WT[w][col][k]) ----------------
__global__ __launch_bounds__(256) void k_prep_w(const float* __restrict__ WA, const float* __restrict__ WB,
    const float* __restrict__ WC, const float* __restrict__ WD, const float* __restrict__ WE,
    u16* __restrict__ WT){
  int idx = blockIdx.x*256 + threadIdx.x;   // 5*16384 total
  if (idx >= 5*16384) return;
  int w = idx >> 14; int rem = idx & 16383; int k = rem >> 7; int c = rem & 127;
  const float* W = (w==0)?WA:(w==1)?WB:(w==2)?WC:(w==3)?WD:WE;
  WT[(size_t)w*16384 + c*128 + k] = f2bf(W[k*128 + c]);
}

// ---------------- K1: node GEMMs: Ah(f32), Bh/Dh/Eh(bf16) = h @ W{A,B,D,E} + b ----------------
__global__ __launch_bounds__(256) void k_node_gemm(const float* __restrict__ h, const u16* __restrict__ WT,
    const float* __restrict__ bA, const float* __restrict__ bB, const float* __restrict__ bD, const float* __restrict__ bE,
    float* __restrict__ Ah, u16* __restrict__ Bh, u16* __restrict__ Dh, u16* __restrict__ Eh){
  __shared__ u16 lh[128*128];
  __shared__ u16 lw[128*128];
  const int tid = threadIdx.x, wv = tid >> 6, l = tid & 63;
  const long row0 = (long)blockIdx.x * 128;
  #pragma unroll
  for (int it = 0; it < 16; ++it){
    int idx = it*256 + tid;
    int r = idx >> 5, c4 = (idx & 31)*4;
    long gr = row0 + r;
    float4 v = {0.f,0.f,0.f,0.f};
    if (gr < N_NODES) v = *(const float4*)(h + gr*DD + c4);
    u16x4 b; b[0]=f2bf(v.x); b[1]=f2bf(v.y); b[2]=f2bf(v.z); b[3]=f2bf(v.w);
    *(u16x4*)&lh[SW(r, c4)] = b;
  }
  const int wsel[4] = {0,1,3,4};
  #pragma unroll 1
  for (int t = 0; t < 4; ++t){
    __syncthreads();   // prev MFMA done before overwriting lw; also covers lh on t=0
    const u16* Wg = WT + (size_t)wsel[t]*16384;
    #pragma unroll
    for (int it = 0; it < 8; ++it){
      int idx = it*256 + tid;
      int j = idx >> 4, ch = (idx & 15)*8;
      *(u16x8*)&lw[SW(j, ch)] = *(const u16x8*)(Wg + j*128 + ch);
    }
    __syncthreads();
    f32x4 acc[2][8];
    #pragma unroll
    for (int m=0;m<2;++m)
      #pragma unroll
      for (int n=0;n<8;++n) acc[m][n] = (f32x4){0.f,0.f,0.f,0.f};
    #pragma unroll
    for (int ks = 0; ks < 4; ++ks){
      int k0 = ks*32 + (l>>4)*8;
      bf16x8 a[2];
      #pragma unroll
      for (int m=0;m<2;++m)
        a[m] = __builtin_bit_cast(bf16x8, *(const u16x8*)&lh[SW(wv*32 + m*16 + (l&15), k0)]);
      #pragma unroll
      for (int n=0;n<8;++n){
        bf16x8 b = __builtin_bit_cast(bf16x8, *(const u16x8*)&lw[SW(n*16 + (l&15), k0)]);
        #pragma unroll
        for (int m=0;m<2;++m)
          acc[m][n] = __builtin_amdgcn_mfma_f32_16x16x32_bf16(a[m], b, acc[m][n], 0,0,0);
      }
    }
    const float* bias = (t==0)?bA:(t==1)?bB:(t==2)?bD:bE;
    #pragma unroll
    for (int n=0;n<8;++n){
      int col = n*16 + (l&15);
      float bv = bias[col];
      #pragma unroll
      for (int m=0;m<2;++m){
        #pragma unroll
        for (int r=0;r<4;++r){
          long gr = row0 + wv*32 + m*16 + (l>>4)*4 + r;
          if (gr < N_NODES){
            float vv = acc[m][n][r] + bv;
            if (t==0)      Ah[gr*DD + col] = vv;
            else if (t==1) Bh[gr*DD + col] = f2bf(vv);
            else if (t==2) Dh[gr*DD + col] = f2bf(vv);
            else           Eh[gr*DD + col] = f2bf(vv);
          }
        }
      }
    }
  }
}

// ---------------- K2: edge pass: Ce=e@WC+bC, e_ij, sigmoid, atomics, BN-e stats ----------------
__global__ __launch_bounds__(256) void k_edge(const float* __restrict__ e, const u16* __restrict__ WTC,
    const float* __restrict__ bC, const int* __restrict__ src, const int* __restrict__ dst,
    const u16* __restrict__ Bh, const u16* __restrict__ Dh, const u16* __restrict__ Eh,
    u16* __restrict__ eij, float* __restrict__ num, float* __restrict__ den, float* __restrict__ deg,
    float* __restrict__ ssum_e, float* __restrict__ sss_e){
  __shared__ u16 le[128*128];
  __shared__ u16 lw[128*128];
  const int tid = threadIdx.x, wv = tid >> 6, l = tid & 63;
  const long row0 = (long)blockIdx.x * 128;   // E divisible by 128: no row guards
  #pragma unroll
  for (int it = 0; it < 16; ++it){
    int idx = it*256 + tid;
    int r = idx >> 5, c4 = (idx & 31)*4;
    float4 v = *(const float4*)(e + (row0 + r)*DD + c4);
    u16x4 b; b[0]=f2bf(v.x); b[1]=f2bf(v.y); b[2]=f2bf(v.z); b[3]=f2bf(v.w);
    *(u16x4*)&le[SW(r, c4)] = b;
  }
  #pragma unroll
  for (int it = 0; it < 8; ++it){
    int idx = it*256 + tid;
    int j = idx >> 4, ch = (idx & 15)*8;
    *(u16x8*)&lw[SW(j, ch)] = *(const u16x8*)(WTC + j*128 + ch);
  }
  __syncthreads();
  f32x4 acc[2][8];
  #pragma unroll
  for (int m=0;m<2;++m)
    #pragma unroll
    for (int n=0;n<8;++n) acc[m][n] = (f32x4){0.f,0.f,0.f,0.f};
  #pragma unroll
  for (int ks = 0; ks < 4; ++ks){
    int k0 = ks*32 + (l>>4)*8;
    bf16x8 a[2];
    #pragma unroll
    for (int m=0;m<2;++m)
      a[m] = __builtin_bit_cast(bf16x8, *(const u16x8*)&le[SW(wv*32 + m*16 + (l&15), k0)]);
    #pragma unroll
    for (int n=0;n<8;++n){
      bf16x8 b = __builtin_bit_cast(bf16x8, *(const u16x8*)&lw[SW(n*16 + (l&15), k0)]);
      #pragma unroll
      for (int m=0;m<2;++m)
        acc[m][n] = __builtin_amdgcn_mfma_f32_16x16x32_bf16(a[m], b, acc[m][n], 0,0,0);
    }
  }
  // epilogue
  const int cb = l & 15, rg = l >> 4;
  float bcv[8];
  #pragma unroll
  for (int n=0;n<8;++n) bcv[n] = bC[n*16 + cb];
  float ssum[8] = {0,0,0,0,0,0,0,0};
  float sss[8]  = {0,0,0,0,0,0,0,0};
  #pragma unroll
  for (int m=0;m<2;++m){
    #pragma unroll
    for (int r=0;r<4;++r){
      long gr = row0 + wv*32 + m*16 + rg*4 + r;
      int sr = src[gr], dr = dst[gr];
      const u16* DhR = Dh + (long)sr*DD;
      const u16* EhR = Eh + (long)dr*DD;
      const u16* BhR = Bh + (long)sr*DD;
      float* numR = num + (long)dr*DD;
      float* denR = den + (long)dr*DD;
      u16* eR = eij + gr*DD;
      if (cb == 0) atomicAdd(deg + dr, 1.0f);
      #pragma unroll
      for (int n=0;n<8;++n){
        int col = n*16 + cb;
        float x = acc[m][n][r] + bcv[n] + bf2f(DhR[col]) + bf2f(EhR[col]);
        float sg = 1.0f/(1.0f + __expf(-x));
        eR[col] = f2bf(x);
        atomicAdd(denR + col, sg);
        atomicAdd(numR + col, sg * bf2f(BhR[col]));
        ssum[n] += x; sss[n] += x*x;
      }
    }
  }
  #pragma unroll
  for (int n=0;n<8;++n){
    float s = ssum[n], q = sss[n];
    s += __shfl_xor(s, 16); s += __shfl_xor(s, 32);
    q += __shfl_xor(q, 16); q += __shfl_xor(q, 32);
    if (l < 16){
      atomicAdd(ssum_e + n*16 + cb, s);
      atomicAdd(sss_e  + n*16 + cb, q);
    }
  }
}

// ---------------- K4: h_agg = where(deg>0, Ah+num/den', h) + BN-h partial stats ----------------
__global__ __launch_bounds__(256) void k_hagg(const float* __restrict__ Ah, const float* __restrict__ num,
    const float* __restrict__ den, const float* __restrict__ deg, const float* __restrict__ h,
    float* __restrict__ hagg, float* __restrict__ ssum_h, float* __restrict__ sss_h){
  const int t = blockIdx.x*256 + threadIdx.x;
  const long stride = (long)gridDim.x*256;
  const int c4 = (t & 31)*4;
  float s0=0,s1=0,s2=0,s3=0,q0=0,q1=0,q2=0,q3=0;
  for (long i = t; i < (long)N_NODES*32; i += stride){
    long row = i >> 5;
    float dg = deg[row];
    float4 ah = ((const float4*)Ah)[i];
    float4 nm = ((const float4*)num)[i];
    float4 dn = ((const float4*)den)[i];
    float4 hv = ((const float4*)h)[i];
    float4 o;
    o.x = (dg > 0.f) ? ah.x + nm.x/((dn.x==0.f)?1.f:dn.x) : hv.x;
    o.y = (dg > 0.f) ? ah.y + nm.y/((dn.y==0.f)?1.f:dn.y) : hv.y;
    o.z = (dg > 0.f) ? ah.z + nm.z/((dn.z==0.f)?1.f:dn.z) : hv.z;
    o.w = (dg > 0.f) ? ah.w + nm.w/((dn.w==0.f)?1.f:dn.w) : hv.w;
    ((float4*)hagg)[i] = o;
    s0+=o.x; s1+=o.y; s2+=o.z; s3+=o.w;
    q0+=o.x*o.x; q1+=o.y*o.y; q2+=o.z*o.z; q3+=o.w*o.w;
  }
  atomicAdd(ssum_h+c4+0,s0); atomicAdd(ssum_h+c4+1,s1); atomicAdd(ssum_h+c4+2,s2); atomicAdd(ssum_h+c4+3,s3);
  atomicAdd(sss_h +c4+0,q0); atomicAdd(sss_h +c4+1,q1); atomicAdd(sss_h +c4+2,q2); atomicAdd(sss_h +c4+3,q3);
}

// ---------------- K35: finalize BN coefficients ----------------
__global__ void k_finalize(const float* __restrict__ stats, const float* __restrict__ ge, const float* __restrict__ be,
    const float* __restrict__ gh, const float* __restrict__ bh, float* __restrict__ coefs){
  int j = threadIdx.x;
  float me = stats[j] * (1.0f/(float)N_EDGES);
  float ve = stats[128+j] * (1.0f/(float)N_EDGES) - me*me;
  float sce = ge[j] * rsqrtf(ve + 1e-5f);
  coefs[j] = sce; coefs[128+j] = be[j] - me*sce;
  float mh = stats[256+j] * (1.0f/(float)N_NODES);
  float vh = stats[384+j] * (1.0f/(float)N_NODES) - mh*mh;
  float sch = gh[j] * rsqrtf(vh + 1e-5f);
  coefs[256+j] = sch; coefs[384+j] = bh[j] - mh*sch;
}

// ---------------- K6: e_out = e + relu(e_ij*scale + shift) ----------------
__global__ __launch_bounds__(256) void k_eout(const float* __restrict__ e, const u16* __restrict__ eij,
    const float* __restrict__ coefs, float* __restrict__ out){
  const int t = blockIdx.x*256 + threadIdx.x;
  const long stride = (long)gridDim.x*256;
  const int c4 = (t & 31)*4;
  float sc0=coefs[c4+0],sc1=coefs[c4+1],sc2=coefs[c4+2],sc3=coefs[c4+3];
  float sh0=coefs[128+c4+0],sh1=coefs[128+c4+1],sh2=coefs[128+c4+2],sh3=coefs[128+c4+3];
  for (long i = t; i < (long)N_EDGES*32; i += stride){
    float4 ev = ((const float4*)e)[i];
    u16x4 bv = ((const u16x4*)eij)[i];
    float4 o;
    o.x = ev.x + fmaxf(bf2f(bv[0])*sc0 + sh0, 0.f);
    o.y = ev.y + fmaxf(bf2f(bv[1])*sc1 + sh1, 0.f);
    o.z = ev.z + fmaxf(bf2f(bv[2])*sc2 + sh2, 0.f);
    o.w = ev.w + fmaxf(bf2f(bv[3])*sc3 + sh3, 0.f);
    ((float4*)out)[i] = o;
  }
}

// ---------------- K7: h_out = h + relu(hagg*scale + shift) ----------------
__global__ __launch_bounds__(256) void k_hout(const float* __restrict__ h, const float* __restrict__ hagg,
    const float* __restrict__ coefs, float* __restrict__ out){
  const int t = blockIdx.x*256 + threadIdx.x;
  const long stride = (long)gridDim.x*256;
  const int c4 = (t & 31)*4;
  float sc0=coefs[c4+0],sc1=coefs[c4+1],sc2=coefs[c4+2],sc3=coefs[c4+3];
  float sh0=coefs[128+c4+0],sh1=coefs[128+c4+1],sh2=coefs[128+c4+2],sh3=coefs[128+c4+3];
  for (long i = t; i < (long)N_NODES*32; i += stride){
    float4 hv = ((const float4*)h)[i];
    float4 av = ((const float4*)hagg)[i];
    float4 o;
    o.x = hv.x + fmaxf(av.x*sc0 + sh0, 0.f);
    o.y = hv.y + fmaxf(av.y*sc1 + sh1, 0.f);
    o.z = hv.z + fmaxf(av.z*sc2 + sh2, 0.f);
    o.w = hv.w + fmaxf(av.w*sc3 + sh3, 0.f);
    ((float4*)out)[i] = o;
  }
}

extern "C" void kernel_launch(void* const* d_in, const int* in_sizes, int n_in,
                              void* d_out, int out_size, void* d_ws, size_t ws_size,
                              hipStream_t stream){
  (void)in_sizes; (void)n_in; (void)out_size; (void)ws_size;
  const float* h  = (const float*)d_in[0];
  const float* e  = (const float*)d_in[1];
  const int* src  = (const int*)d_in[2];
  const int* dst  = (const int*)d_in[3];
  const float* WA = (const float*)d_in[4];  const float* bA = (const float*)d_in[5];
  const float* WB = (const float*)d_in[6];  const float* bB = (const float*)d_in[7];
  const float* WC = (const float*)d_in[8];  const float* bC = (const float*)d_in[9];
  const float* WD = (const float*)d_in[10]; const float* bD = (const float*)d_in[11];
  const float* WE = (const float*)d_in[12]; const float* bE = (const float*)d_in[13];
  const float* gamma_h = (const float*)d_in[14]; const float* beta_h = (const float*)d_in[15];
  const float* gamma_e = (const float*)d_in[16]; const float* beta_e = (const float*)d_in[17];

  char* ws = (char*)d_ws;
  size_t off = 0;
  u16*   WT   = (u16*)(ws + off);   off += (size_t)5*16384*2;          // 163,840
  float* Ah   = (float*)(ws + off); off += (size_t)N_NODES*DD*4;       // 25.6 MB
  u16*   Bh   = (u16*)(ws + off);   off += (size_t)N_NODES*DD*2;       // 12.8 MB
  u16*   Dh   = (u16*)(ws + off);   off += (size_t)N_NODES*DD*2;
  u16*   Eh   = (u16*)(ws + off);   off += (size_t)N_NODES*DD*2;
  u16*   eij  = (u16*)(ws + off);   off += (size_t)N_EDGES*DD*2;       // 204.8 MB
  float* hagg = (float*)(ws + off); off += (size_t)N_NODES*DD*4;
  size_t zoff = off;                                                    // zero region start
  float* num  = (float*)(ws + off); off += (size_t)N_NODES*DD*4;
  float* den  = (float*)(ws + off); off += (size_t)N_NODES*DD*4;
  float* deg  = (float*)(ws + off); off += 200192;                      // 50000*4 padded
  float* stats= (float*)(ws + off); off += 4096;                        // sums(512) + coefs(512)

  hipMemsetAsync(ws + zoff, 0, off - zoff, stream);

  k_prep_w<<<320, 256, 0, stream>>>(WA, WB, WC, WD, WE, WT);
  k_node_gemm<<<(N_NODES + 127)/128, 256, 0, stream>>>(h, WT, bA, bB, bD, bE, Ah, Bh, Dh, Eh);
  k_edge<<<N_EDGES/128, 256, 0, stream>>>(e, WT + (size_t)2*16384, bC, src, dst, Bh, Dh, Eh,
                                          eij, num, den, deg, stats, stats + 128);
  k_hagg<<<512, 256, 0, stream>>>(Ah, num, den, deg, h, hagg, stats + 256, stats + 384);
  k_finalize<<<1, 128, 0, stream>>>(stats, gamma_e, beta_e, gamma_h, beta_h, stats + 512);
  k_eout<<<2048, 256, 0, stream>>>(e, eij, stats + 512, (float*)d_out + (size_t)N_NODES*DD);
  k_hout<<<256, 256, 0, stream>>>(h, hagg, stats + 512 + 256, (float*)d_out);
}

// Round 2
// 1802.172 us; speedup vs baseline: 1.4058x; 1.4058x over previous
//
#include <hip/hip_runtime.h>

typedef __bf16 bf16x8 __attribute__((ext_vector_type(8)));
typedef float f32x4 __attribute__((ext_vector_type(4)));
typedef unsigned short u16x8 __attribute__((ext_vector_type(8)));
typedef unsigned short u16x4 __attribute__((ext_vector_type(4)));
typedef unsigned short u16x2 __attribute__((ext_vector_type(2)));
typedef unsigned short u16;

#define N_NODES 50000
#define N_EDGES 800000
#define DD 128

__device__ __forceinline__ u16 f2bf(float f){
  unsigned int u = __float_as_uint(f);
  unsigned int r = (u + 0x7FFFu + ((u >> 16) & 1u)) >> 16;
  return (u16)r;
}
__device__ __forceinline__ float bf2f(u16 s){
  return __uint_as_float(((unsigned int)s) << 16);
}
// XOR swizzle inside [128][128] u16 LDS tile; 8-elem (16B) chunks stay contiguous.
__device__ __forceinline__ int SW(int row, int k){ return row*128 + (k ^ ((row & 7) << 3)); }

// ---------------- K0: W -> bf16 transposed (WT[w][col][k]) ----------------
__global__ __launch_bounds__(256) void k_prep_w(const float* __restrict__ WA, const float* __restrict__ WB,
    const float* __restrict__ WC, const float* __restrict__ WD, const float* __restrict__ WE,
    u16* __restrict__ WT){
  int idx = blockIdx.x*256 + threadIdx.x;
  if (idx >= 5*16384) return;
  int w = idx >> 14; int rem = idx & 16383; int k = rem >> 7; int c = rem & 127;
  const float* W = (w==0)?WA:(w==1)?WB:(w==2)?WC:(w==3)?WD:WE;
  WT[(size_t)w*16384 + c*128 + k] = f2bf(W[k*128 + c]);
}

// ---------------- K1: node GEMMs: Ah(f32), Bh/Dh/Eh(bf16) ----------------
__global__ __launch_bounds__(256) void k_node_gemm(const float* __restrict__ h, const u16* __restrict__ WT,
    const float* __restrict__ bA, const float* __restrict__ bB, const float* __restrict__ bD, const float* __restrict__ bE,
    float* __restrict__ Ah, u16* __restrict__ Bh, u16* __restrict__ Dh, u16* __restrict__ Eh){
  __shared__ u16 lh[128*128];
  __shared__ u16 lw[128*128];
  const int tid = threadIdx.x, wv = tid >> 6, l = tid & 63;
  const long row0 = (long)blockIdx.x * 128;
  #pragma unroll
  for (int it = 0; it < 16; ++it){
    int idx = it*256 + tid;
    int r = idx >> 5, c4 = (idx & 31)*4;
    long gr = row0 + r;
    float4 v = {0.f,0.f,0.f,0.f};
    if (gr < N_NODES) v = *(const float4*)(h + gr*DD + c4);
    u16x4 b; b[0]=f2bf(v.x); b[1]=f2bf(v.y); b[2]=f2bf(v.z); b[3]=f2bf(v.w);
    *(u16x4*)&lh[SW(r, c4)] = b;
  }
  const int wsel[4] = {0,1,3,4};
  #pragma unroll 1
  for (int t = 0; t < 4; ++t){
    __syncthreads();
    const u16* Wg = WT + (size_t)wsel[t]*16384;
    #pragma unroll
    for (int it = 0; it < 8; ++it){
      int idx = it*256 + tid;
      int j = idx >> 4, ch = (idx & 15)*8;
      *(u16x8*)&lw[SW(j, ch)] = *(const u16x8*)(Wg + j*128 + ch);
    }
    __syncthreads();
    f32x4 acc[2][8];
    #pragma unroll
    for (int m=0;m<2;++m)
      #pragma unroll
      for (int n=0;n<8;++n) acc[m][n] = (f32x4){0.f,0.f,0.f,0.f};
    #pragma unroll
    for (int ks = 0; ks < 4; ++ks){
      int k0 = ks*32 + (l>>4)*8;
      bf16x8 a[2];
      #pragma unroll
      for (int m=0;m<2;++m)
        a[m] = __builtin_bit_cast(bf16x8, *(const u16x8*)&lh[SW(wv*32 + m*16 + (l&15), k0)]);
      #pragma unroll
      for (int n=0;n<8;++n){
        bf16x8 b = __builtin_bit_cast(bf16x8, *(const u16x8*)&lw[SW(n*16 + (l&15), k0)]);
        #pragma unroll
        for (int m=0;m<2;++m)
          acc[m][n] = __builtin_amdgcn_mfma_f32_16x16x32_bf16(a[m], b, acc[m][n], 0,0,0);
      }
    }
    const float* bias = (t==0)?bA:(t==1)?bB:(t==2)?bD:bE;
    #pragma unroll
    for (int n=0;n<8;++n){
      int col = n*16 + (l&15);
      float bv = bias[col];
      #pragma unroll
      for (int m=0;m<2;++m){
        #pragma unroll
        for (int r=0;r<4;++r){
          long gr = row0 + wv*32 + m*16 + (l>>4)*4 + r;
          if (gr < N_NODES){
            float vv = acc[m][n][r] + bv;
            if (t==0)      Ah[gr*DD + col] = vv;
            else if (t==1) Bh[gr*DD + col] = f2bf(vv);
            else if (t==2) Dh[gr*DD + col] = f2bf(vv);
            else           Eh[gr*DD + col] = f2bf(vv);
          }
        }
      }
    }
  }
}

// ---------------- sort: histogram ----------------
__global__ __launch_bounds__(256) void k_hist(const int* __restrict__ dst, int* __restrict__ cnt){
  int g = blockIdx.x*256 + threadIdx.x;
  if (g < N_EDGES) atomicAdd(cnt + dst[g], 1);
}

// ---------------- sort: single-block prefix scan (50000 elems) ----------------
__global__ __launch_bounds__(1024) void k_scan(const int* __restrict__ cnt, int* __restrict__ rowptr,
                                               int* __restrict__ cursor){
  __shared__ int wsum[16];
  __shared__ int carry_s;
  const int tid = threadIdx.x, lane = tid & 63, wv = tid >> 6;
  if (tid == 0){ carry_s = 0; rowptr[0] = 0; }
  __syncthreads();
  for (int base = 0; base < N_NODES; base += 1024){
    int i = base + tid;
    int v = (i < N_NODES) ? cnt[i] : 0;
    int x = v;
    #pragma unroll
    for (int d = 1; d < 64; d <<= 1){
      int y = __shfl_up(x, d);
      if (lane >= d) x += y;
    }
    if (lane == 63) wsum[wv] = x;
    __syncthreads();
    int woff = 0;
    #pragma unroll
    for (int k = 0; k < 16; ++k) if (k < wv) woff += wsum[k];
    int incl = carry_s + woff + x;
    if (i < N_NODES){ rowptr[i+1] = incl; cursor[i] = incl - v; }
    __syncthreads();
    if (tid == 1023) carry_s = incl;
    __syncthreads();
  }
}

// ---------------- sort: scatter (rank = sorted position of edge g) ----------------
__global__ __launch_bounds__(256) void k_scatter(const int* __restrict__ src, const int* __restrict__ dst,
    int* __restrict__ cursor, int* __restrict__ rank, int* __restrict__ src_s){
  int g = blockIdx.x*256 + threadIdx.x;
  if (g < N_EDGES){
    int pos = atomicAdd(cursor + dst[g], 1);
    rank[g] = pos;
    src_s[pos] = src[g];
  }
}

// ---------------- E1: edge GEMM: eij_s[rank[g]] = bf16(e[g]@WC + bC) ----------------
__global__ __launch_bounds__(256) void k_egemm(const float* __restrict__ e, const u16* __restrict__ WTC,
    const float* __restrict__ bC, const int* __restrict__ rank, u16* __restrict__ eij_s){
  __shared__ u16 le[128*128];
  __shared__ u16 lw[128*128];
  __shared__ int rnk[128];
  const int tid = threadIdx.x, wv = tid >> 6, l = tid & 63;
  const long row0 = (long)blockIdx.x * 128;
  if (tid < 128) rnk[tid] = rank[row0 + tid];
  #pragma unroll
  for (int it = 0; it < 16; ++it){
    int idx = it*256 + tid;
    int r = idx >> 5, c4 = (idx & 31)*4;
    float4 v = *(const float4*)(e + (row0 + r)*DD + c4);
    u16x4 b; b[0]=f2bf(v.x); b[1]=f2bf(v.y); b[2]=f2bf(v.z); b[3]=f2bf(v.w);
    *(u16x4*)&le[SW(r, c4)] = b;
  }
  #pragma unroll
  for (int it = 0; it < 8; ++it){
    int idx = it*256 + tid;
    int j = idx >> 4, ch = (idx & 15)*8;
    *(u16x8*)&lw[SW(j, ch)] = *(const u16x8*)(WTC + j*128 + ch);
  }
  __syncthreads();
  f32x4 acc[2][8];
  #pragma unroll
  for (int m=0;m<2;++m)
    #pragma unroll
    for (int n=0;n<8;++n) acc[m][n] = (f32x4){0.f,0.f,0.f,0.f};
  #pragma unroll
  for (int ks = 0; ks < 4; ++ks){
    int k0 = ks*32 + (l>>4)*8;
    bf16x8 a[2];
    #pragma unroll
    for (int m=0;m<2;++m)
      a[m] = __builtin_bit_cast(bf16x8, *(const u16x8*)&le[SW(wv*32 + m*16 + (l&15), k0)]);
    #pragma unroll
    for (int n=0;n<8;++n){
      bf16x8 b = __builtin_bit_cast(bf16x8, *(const u16x8*)&lw[SW(n*16 + (l&15), k0)]);
      #pragma unroll
      for (int m=0;m<2;++m)
        acc[m][n] = __builtin_amdgcn_mfma_f32_16x16x32_bf16(a[m], b, acc[m][n], 0,0,0);
    }
  }
  const int cb = l & 15, rg = l >> 4;
  float bcv[8];
  #pragma unroll
  for (int n=0;n<8;++n) bcv[n] = bC[n*16 + cb];
  __syncthreads();   // all MFMA reads of le done
  #pragma unroll
  for (int m=0;m<2;++m)
    #pragma unroll
    for (int n=0;n<8;++n)
      #pragma unroll
      for (int r=0;r<4;++r)
        le[SW(wv*32 + m*16 + rg*4 + r, n*16 + cb)] = f2bf(acc[m][n][r] + bcv[n]);
  __syncthreads();
  #pragma unroll
  for (int it = 0; it < 8; ++it){
    int idx = it*256 + tid;
    int r = idx >> 4, ch = (idx & 15)*8;
    *(u16x8*)(eij_s + (long)rnk[r]*DD + ch) = *(const u16x8*)&le[r*128 + (ch ^ ((r & 7) << 3))];
  }
}

// ---------------- E2: per-node aggregate + h_agg + BN stats (no atomics on num/den) ----------------
__global__ __launch_bounds__(256) void k_agg(const int* __restrict__ rowptr, const int* __restrict__ src_s,
    const u16* __restrict__ eij_s, const u16* __restrict__ Bh, const u16* __restrict__ Dh,
    const u16* __restrict__ Eh, const float* __restrict__ Ah, const float* __restrict__ h,
    float* __restrict__ hagg, float* __restrict__ ssum_e, float* __restrict__ sss_e,
    float* __restrict__ ssum_h, float* __restrict__ sss_h){
  const int l = threadIdx.x & 63;
  const int wave = (blockIdx.x*256 + threadIdx.x) >> 6;
  const int nw = (gridDim.x*256) >> 6;
  const int c0 = l*2;
  float se0=0,se1=0,qe0=0,qe1=0, sh0=0,sh1=0,qh0=0,qh1=0;
  for (int n = wave; n < N_NODES; n += nw){
    const int r0 = rowptr[n], r1 = rowptr[n+1];
    const float eh0 = bf2f(Eh[(long)n*DD + c0]);
    const float eh1 = bf2f(Eh[(long)n*DD + c0 + 1]);
    float num0=0,num1=0,den0=0,den1=0;
    for (int j = r0; j < r1; ++j){
      const int s = src_s[j];
      u16x2 ce = *(const u16x2*)(eij_s + (long)j*DD + c0);
      u16x2 dh = *(const u16x2*)(Dh + (long)s*DD + c0);
      u16x2 bh = *(const u16x2*)(Bh + (long)s*DD + c0);
      float x0 = bf2f(ce[0]) + bf2f(dh[0]) + eh0;
      float x1 = bf2f(ce[1]) + bf2f(dh[1]) + eh1;
      float g0 = 1.0f/(1.0f + __expf(-x0));
      float g1 = 1.0f/(1.0f + __expf(-x1));
      den0 += g0; den1 += g1;
      num0 += g0 * bf2f(bh[0]); num1 += g1 * bf2f(bh[1]);
      se0 += x0; se1 += x1; qe0 += x0*x0; qe1 += x1*x1;
    }
    float2 o;
    if (r1 > r0){
      float2 ahv = *(const float2*)(Ah + (long)n*DD + c0);
      o.x = ahv.x + num0/den0;
      o.y = ahv.y + num1/den1;
    } else {
      o = *(const float2*)(h + (long)n*DD + c0);
    }
    *(float2*)(hagg + (long)n*DD + c0) = o;
    sh0 += o.x; sh1 += o.y; qh0 += o.x*o.x; qh1 += o.y*o.y;
  }
  atomicAdd(ssum_e + c0, se0); atomicAdd(ssum_e + c0 + 1, se1);
  atomicAdd(sss_e  + c0, qe0); atomicAdd(sss_e  + c0 + 1, qe1);
  atomicAdd(ssum_h + c0, sh0); atomicAdd(ssum_h + c0 + 1, sh1);
  atomicAdd(sss_h  + c0, qh0); atomicAdd(sss_h  + c0 + 1, qh1);
}

// ---------------- finalize BN coefficients ----------------
__global__ void k_finalize(const float* __restrict__ stats, const float* __restrict__ ge, const float* __restrict__ be,
    const float* __restrict__ gh, const float* __restrict__ bh, float* __restrict__ coefs){
  int j = threadIdx.x;
  float me = stats[j] * (1.0f/(float)N_EDGES);
  float ve = stats[128+j] * (1.0f/(float)N_EDGES) - me*me;
  float sce = ge[j] * rsqrtf(ve + 1e-5f);
  coefs[j] = sce; coefs[128+j] = be[j] - me*sce;
  float mh = stats[256+j] * (1.0f/(float)N_NODES);
  float vh = stats[384+j] * (1.0f/(float)N_NODES) - mh*mh;
  float sch = gh[j] * rsqrtf(vh + 1e-5f);
  coefs[256+j] = sch; coefs[384+j] = bh[j] - mh*sch;
}

// ---------------- e_out = e + relu(bn(ce + Dh[src] + Eh[dst])) ----------------
__global__ __launch_bounds__(256) void k_eout(const float* __restrict__ e, const u16* __restrict__ eij_s,
    const int* __restrict__ rank, const int* __restrict__ src, const int* __restrict__ dst,
    const u16* __restrict__ Dh, const u16* __restrict__ Eh, const float* __restrict__ coefs,
    float* __restrict__ out){
  const long t0 = blockIdx.x*256 + threadIdx.x;
  const long stride = (long)gridDim.x*256;
  for (long i = t0; i < (long)N_EDGES*32; i += stride){
    long g = i >> 5; int cq = (int)(i & 31)*4;
    int rk = rank[g], s = src[g], d = dst[g];
    float4 ev = ((const float4*)e)[i];
    u16x4 ce = *(const u16x4*)(eij_s + (long)rk*DD + cq);
    u16x4 dh = *(const u16x4*)(Dh + (long)s*DD + cq);
    u16x4 eh = *(const u16x4*)(Eh + (long)d*DD + cq);
    float4 sc = ((const float4*)coefs)[cq>>2];
    float4 sh = ((const float4*)(coefs+128))[cq>>2];
    float4 o;
    o.x = ev.x + fmaxf((bf2f(ce[0])+bf2f(dh[0])+bf2f(eh[0]))*sc.x + sh.x, 0.f);
    o.y = ev.y + fmaxf((bf2f(ce[1])+bf2f(dh[1])+bf2f(eh[1]))*sc.y + sh.y, 0.f);
    o.z = ev.z + fmaxf((bf2f(ce[2])+bf2f(dh[2])+bf2f(eh[2]))*sc.z + sh.z, 0.f);
    o.w = ev.w + fmaxf((bf2f(ce[3])+bf2f(dh[3])+bf2f(eh[3]))*sc.w + sh.w, 0.f);
    ((float4*)out)[i] = o;
  }
}

// ---------------- h_out = h + relu(bn(hagg)) ----------------
__global__ __launch_bounds__(256) void k_hout(const float* __restrict__ h, const float* __restrict__ hagg,
    const float* __restrict__ coefs, float* __restrict__ out){
  const int t = blockIdx.x*256 + threadIdx.x;
  const long stride = (long)gridDim.x*256;
  const int c4 = (t & 31)*4;
  float sc0=coefs[c4+0],sc1=coefs[c4+1],sc2=coefs[c4+2],sc3=coefs[c4+3];
  float sh0=coefs[128+c4+0],sh1=coefs[128+c4+1],sh2=coefs[128+c4+2],sh3=coefs[128+c4+3];
  for (long i = t; i < (long)N_NODES*32; i += stride){
    float4 hv = ((const float4*)h)[i];
    float4 av = ((const float4*)hagg)[i];
    float4 o;
    o.x = hv.x + fmaxf(av.x*sc0 + sh0, 0.f);
    o.y = hv.y + fmaxf(av.y*sc1 + sh1, 0.f);
    o.z = hv.z + fmaxf(av.z*sc2 + sh2, 0.f);
    o.w = hv.w + fmaxf(av.w*sc3 + sh3, 0.f);
    ((float4*)out)[i] = o;
  }
}

extern "C" void kernel_launch(void* const* d_in, const int* in_sizes, int n_in,
                              void* d_out, int out_size, void* d_ws, size_t ws_size,
                              hipStream_t stream){
  (void)in_sizes; (void)n_in; (void)out_size; (void)ws_size;
  const float* h  = (const float*)d_in[0];
  const float* e  = (const float*)d_in[1];
  const int* src  = (const int*)d_in[2];
  const int* dst  = (const int*)d_in[3];
  const float* WA = (const float*)d_in[4];  const float* bA = (const float*)d_in[5];
  const float* WB = (const float*)d_in[6];  const float* bB = (const float*)d_in[7];
  const float* WC = (const float*)d_in[8];  const float* bC = (const float*)d_in[9];
  const float* WD = (const float*)d_in[10]; const float* bD = (const float*)d_in[11];
  const float* WE = (const float*)d_in[12]; const float* bE = (const float*)d_in[13];
  const float* gamma_h = (const float*)d_in[14]; const float* beta_h = (const float*)d_in[15];
  const float* gamma_e = (const float*)d_in[16]; const float* beta_e = (const float*)d_in[17];

  char* ws = (char*)d_ws;
  size_t off = 0;
  u16*   WT    = (u16*)(ws + off);   off += (size_t)5*16384*2;         // 160 KB
  float* Ah    = (float*)(ws + off); off += (size_t)N_NODES*DD*4;      // 25.6 MB
  u16*   Bh    = (u16*)(ws + off);   off += (size_t)N_NODES*DD*2;      // 12.8 MB
  u16*   Dh    = (u16*)(ws + off);   off += (size_t)N_NODES*DD*2;
  u16*   Eh    = (u16*)(ws + off);   off += (size_t)N_NODES*DD*2;
  u16*   eij_s = (u16*)(ws + off);   off += (size_t)N_EDGES*DD*2;      // 204.8 MB
  float* hagg  = (float*)(ws + off); off += (size_t)N_NODES*DD*4;      // 25.6 MB
  int*   rank  = (int*)(ws + off);   off += (size_t)N_EDGES*4;         // 3.2 MB
  int*   src_s = (int*)(ws + off);   off += (size_t)N_EDGES*4;         // 3.2 MB
  int*   rowptr= (int*)(ws + off);   off += 200704;                    // 50001 ints, padded
  int*   cursor= (int*)(ws + off);   off += 200704;
  size_t zoff = off;                                                   // zero region
  int*   cnt   = (int*)(ws + off);   off += 200704;                    // 50000 ints
  float* stats = (float*)(ws + off); off += 4096;                      // 512 sums + 512 coefs

  // zero: cnt + the 512 stat sums (coefs overwritten by k_finalize)
  hipMemsetAsync(ws + zoff, 0, 200704 + 2048, stream);

  k_prep_w<<<320, 256, 0, stream>>>(WA, WB, WC, WD, WE, WT);
  k_hist<<<(N_EDGES+255)/256, 256, 0, stream>>>(dst, cnt);
  k_scan<<<1, 1024, 0, stream>>>(cnt, rowptr, cursor);
  k_scatter<<<(N_EDGES+255)/256, 256, 0, stream>>>(src, dst, cursor, rank, src_s);
  k_node_gemm<<<(N_NODES + 127)/128, 256, 0, stream>>>(h, WT, bA, bB, bD, bE, Ah, Bh, Dh, Eh);
  k_egemm<<<N_EDGES/128, 256, 0, stream>>>(e, WT + (size_t)2*16384, bC, rank, eij_s);
  k_agg<<<3125, 256, 0, stream>>>(rowptr, src_s, eij_s, Bh, Dh, Eh, Ah, h, hagg,
                                  stats, stats + 128, stats + 256, stats + 384);
  k_finalize<<<1, 128, 0, stream>>>(stats, gamma_e, beta_e, gamma_h, beta_h, stats + 512);
  k_eout<<<4096, 256, 0, stream>>>(e, eij_s, rank, src, dst, Dh, Eh, stats + 512,
                                   (float*)d_out + (size_t)N_NODES*DD);
  k_hout<<<256, 256, 0, stream>>>(h, hagg, stats + 512 + 256, (float*)d_out);
}